// Round 6
// baseline (243.721 us; speedup 1.0000x reference)
//
#include <hip/hip_runtime.h>

typedef unsigned short u16;
typedef unsigned int u32;
typedef __bf16 bf16x8 __attribute__((ext_vector_type(8)));
typedef float f32x4 __attribute__((ext_vector_type(4)));
typedef u16 u16x4 __attribute__((ext_vector_type(4)));

#define S_LEN 2048
#define NH 16
#define DH 64
#define DM 1024

#define GLDS(gp, lp) __builtin_amdgcn_global_load_lds( \
    (const __attribute__((address_space(1))) void*)(gp), \
    (__attribute__((address_space(3))) void*)(lp), 16, 0, 0)

template <int N> struct IC { static constexpr int v = N; };

__device__ __forceinline__ u16 f2bf(float f) {
  unsigned u = __float_as_uint(f);
  u += 0x7FFFu + ((u >> 16) & 1u);
  return (u16)(u >> 16);
}
__device__ __forceinline__ float bf2f(u16 h) {
  return __uint_as_float(((unsigned)h) << 16);
}

// ---------------- convert f32 -> bf16 (x, Wqkv, Wo in one launch) ----------------
__global__ __launch_bounds__(256) void conv3_kernel(const float* __restrict__ a,
                                                    const float* __restrict__ wb,
                                                    const float* __restrict__ wc,
                                                    u16* __restrict__ oa,
                                                    u16* __restrict__ ob,
                                                    u16* __restrict__ oc) {
  int bid = blockIdx.x;
  const float* in;
  u16* out;
  int idx;
  if (bid < 2048)      { in = a;  out = oa; idx = bid; }
  else if (bid < 3584) { in = wb; out = ob; idx = bid - 2048; }
  else                 { in = wc; out = oc; idx = bid - 3584; }
  int i = idx * 2048 + threadIdx.x * 8;
  float4 v0 = *(const float4*)(in + i);
  float4 v1 = *(const float4*)(in + i + 4);
  u16x4 o0, o1;
  o0.x = f2bf(v0.x); o0.y = f2bf(v0.y); o0.z = f2bf(v0.z); o0.w = f2bf(v0.w);
  o1.x = f2bf(v1.x); o1.y = f2bf(v1.y); o1.z = f2bf(v1.z); o1.w = f2bf(v1.w);
  *(u16x4*)(out + i) = o0;
  *(u16x4*)(out + i + 4) = o1;
}

// ---------------- bf16 GEMM: C[M][N] = A[M][K] * B[N][K]^T ----------------
// 128x128 tile, BK=32, 4 waves, 2-phase double-buffered global_load_lds:
// stage(t+1) issued before compute(t); single vmcnt(0)+s_barrier per K-step.
template <int OUTF32>
__global__ __launch_bounds__(256) void gemm_bt(const u16* __restrict__ A,
                                               const u16* __restrict__ B,
                                               void* __restrict__ C,
                                               int N, int K) {
  __shared__ __align__(16) u16 smem[16384];  // 2 bufs x (A 4096 + B 4096)
  int tid = threadIdx.x;
  int w = tid >> 6, l = tid & 63, lg = l >> 4, lr = l & 15;
  int m0 = blockIdx.y * 128, n0 = blockIdx.x * 128;
  int wm = (w >> 1) * 64, wn = (w & 1) * 64;
  int NK = K >> 5;

  int srow0 = w * 16 + (l >> 2);
  int srow1 = srow0 + 64;
  int scol = (l & 3) * 8;
  const u16* gA0 = A + (size_t)(m0 + srow0) * K + scol;
  const u16* gA1 = A + (size_t)(m0 + srow1) * K + scol;
  const u16* gB0 = B + (size_t)(n0 + srow0) * K + scol;
  const u16* gB1 = B + (size_t)(n0 + srow1) * K + scol;

  auto stage = [&](int p) {
    u16* ab = smem + p * 8192;
    u16* bb = ab + 4096;
    GLDS(gA0, ab + w * 512);
    GLDS(gA1, ab + (4 + w) * 512);
    GLDS(gB0, bb + w * 512);
    GLDS(gB1, bb + (4 + w) * 512);
  };
  auto adv = [&]() { gA0 += 32; gA1 += 32; gB0 += 32; gB1 += 32; };

  f32x4 zero4 = {0.f, 0.f, 0.f, 0.f};
  f32x4 acc[4][4];
#pragma unroll
  for (int mt = 0; mt < 4; ++mt)
#pragma unroll
    for (int nt = 0; nt < 4; ++nt) acc[mt][nt] = zero4;

  stage(0);
  adv();
  __syncthreads();  // prologue: full drain ok

  int p = 0;
  for (int kt = 0; kt < NK; ++kt) {
    bool pre = (kt + 1 < NK);
    if (pre) { stage(p ^ 1); adv(); }

    const u16* ab = smem + p * 8192;
    const u16* bb = ab + 4096;
    bf16x8 af[4], bfr[4];
#pragma unroll
    for (int mt = 0; mt < 4; ++mt)
      af[mt] = *(const bf16x8*)(ab + (wm + mt * 16 + lr) * 32 + lg * 8);
#pragma unroll
    for (int nt = 0; nt < 4; ++nt)
      bfr[nt] = *(const bf16x8*)(bb + (wn + nt * 16 + lr) * 32 + lg * 8);
    __builtin_amdgcn_s_setprio(1);
#pragma unroll
    for (int mt = 0; mt < 4; ++mt)
#pragma unroll
      for (int nt = 0; nt < 4; ++nt)
        acc[mt][nt] = __builtin_amdgcn_mfma_f32_16x16x32_bf16(af[mt], bfr[nt], acc[mt][nt], 0, 0, 0);
    __builtin_amdgcn_s_setprio(0);

    if (pre) {
      asm volatile("s_waitcnt vmcnt(0)" ::: "memory");
      __builtin_amdgcn_s_barrier();
    }
    p ^= 1;
  }

#pragma unroll
  for (int mt = 0; mt < 4; ++mt)
#pragma unroll
    for (int nt = 0; nt < 4; ++nt)
#pragma unroll
      for (int r = 0; r < 4; ++r) {
        int row = m0 + wm + mt * 16 + lg * 4 + r;
        int col = n0 + wn + nt * 16 + lr;
        float v = acc[mt][nt][r];
        if (OUTF32) ((float*)C)[(size_t)row * N + col] = v;
        else        ((u16*)C)[(size_t)row * N + col] = f2bf(v);
      }
}

// ---------------- RoPE + head-major layout + V transpose ----------------
// Q is pre-scaled by (1/sqrt(dh)) * log2(e) here (attn works in exp2 domain).
__global__ __launch_bounds__(256) void rope_kernel(const u16* __restrict__ qkv,
                                                   const float* __restrict__ pi_gate_logit,
                                                   u16* __restrict__ qrot,
                                                   u16* __restrict__ krot,
                                                   u16* __restrict__ vt) {
  int st = blockIdx.x;   // s tile (0..31)
  int bh = blockIdx.y;   // b*16+h
  int h = bh & 15;
  int t = threadIdx.x;
  int sl = t >> 2;       // 0..63
  int pb = t & 3;
  int d0 = pb * 16;
  int s = st * 64 + sl;
  int b = bh >> 4;
  size_t rowg = (size_t)(b * S_LEN + s) * (3 * DM) + h * DH + d0;

  float pg = 1.0f / (1.0f + __expf(-pi_gate_logit[h]));
  float spos = (float)s;
  float cs[8], sn[8];
#pragma unroll
  for (int j = 0; j < 8; ++j) {
    float p = (float)(pb * 8 + j);
    float fr = exp2f((1.0f - p * 0.03125f) * 1.6514961294723187f);  // pi^(1-p/32)
    float th = (spos * fr) * pg;
    float rev = th * 0.15915494309189535f;
    rev = rev - floorf(rev);
    cs[j] = __builtin_amdgcn_cosf(rev);
    sn[j] = __builtin_amdgcn_sinf(rev);
  }

#pragma unroll
  for (int which = 0; which < 2; ++which) {
    const u16* src = qkv + rowg + (size_t)which * DM;
    float sc = which ? 1.0f : 0.18033688011111772f;  // 0.125 * log2(e)
    u16 in[16], ou[16];
    *(bf16x8*)(in)     = *(const bf16x8*)(src);
    *(bf16x8*)(in + 8) = *(const bf16x8*)(src + 8);
#pragma unroll
    for (int j = 0; j < 8; ++j) {
      float t1 = bf2f(in[2 * j]), t2 = bf2f(in[2 * j + 1]);
      ou[2 * j]     = f2bf((t1 * cs[j] - t2 * sn[j]) * sc);
      ou[2 * j + 1] = f2bf((t1 * sn[j] + t2 * cs[j]) * sc);
    }
    u16* dst = (which ? krot : qrot) + ((size_t)bh * S_LEN + s) * DH + d0;
    *(bf16x8*)(dst)     = *(bf16x8*)(ou);
    *(bf16x8*)(dst + 8) = *(bf16x8*)(ou + 8);
  }

  {
    const u16* src = qkv + rowg + 2 * DM;
    u16 in[16];
    *(bf16x8*)(in)     = *(const bf16x8*)(src);
    *(bf16x8*)(in + 8) = *(const bf16x8*)(src + 8);
#pragma unroll
    for (int e = 0; e < 16; ++e)
      vt[((size_t)bh * DH + d0 + e) * S_LEN + st * 64 + sl] = in[e];
  }
}

// ---------------- flash attention ----------------
// exp2-domain online softmax, swapped QK^T (lane owns a q-row), decay bias as
// MFMA C-init, precomputed swizzled LDS bases, counted-wait barriers so the
// one-tile-ahead global prefetch stays in flight across s_barrier.
__global__ __launch_bounds__(256, 3) void attn_kernel(const u16* __restrict__ qrot,
                                                      const u16* __restrict__ krot,
                                                      const u16* __restrict__ vt,
                                                      const float* __restrict__ log_xi,
                                                      const float* __restrict__ e_gate_logit,
                                                      u16* __restrict__ attnout) {
  int bh = blockIdx.x;
  int qt = 31 - blockIdx.y;  // heavy-first
  int b = bh >> 4, h = bh & 15;
  int tid = threadIdx.x, w = tid >> 6, l = tid & 63, lg = l >> 4, lr = l & 15;
  int q0 = qt * 64;
  int il = w * 16 + lr;

  const float L2E = 1.4426950408889634f;
  float eg = 1.0f / (1.0f + __expf(-e_gate_logit[h]));
  float cdec2 = eg * __expf(-log_xi[h]) * L2E;  // (e_g/xi) * log2e

  __shared__ __align__(16) unsigned char smem[40960];
  // [0:16384) K bufs, [16384:32768) V bufs, [32768:40960) pbuf per wave
  unsigned char* pbuf = smem + 32768 + (w << 11);

  // ---- precomputed per-lane LDS bases (zero per-tile address VALU) ----
  int swz = lr & 7;
  unsigned char* kvb[2];
  kvb[0] = smem + lr * 128 + ((lg ^ swz) << 4);
  kvb[1] = smem + lr * 128 + (((lg + 4) ^ swz) << 4);
  int lg0 = lg & 1, lg1 = lg >> 1;
  unsigned char* pw[4];
#pragma unroll
  for (int nt = 0; nt < 4; ++nt)
    pw[nt] = pbuf + lr * 128 + lg0 * 8 + ((lg1 ^ (lr & 1)) << 4) +
             ((nt ^ ((lr >> 1) & 3)) << 5);
  const unsigned char* prd[2];
  prd[0] = pbuf + lr * 128 + ((lg ^ swz) << 4);
  prd[1] = pbuf + lr * 128 + (((lg + 4) ^ swz) << 4);

  // ---- staging geometry ----
  int row0 = tid >> 3, sl0 = tid & 7;  // rows 0..31; +32 for second chunk
  unsigned char* sp = smem + row0 * 128 + ((sl0 ^ (row0 & 7)) << 4);

  const size_t bhS = (size_t)bh * S_LEN;
  const u16* kg0 = krot + bhS * DH + row0 * DH + sl0 * 8;
  const u16* kg1 = kg0 + 32 * DH;
  const u16* vg0 = vt + (size_t)bh * DH * S_LEN + (size_t)row0 * S_LEN + sl0 * 8;
  const u16* vg1 = vg0 + (size_t)32 * S_LEN;

  bf16x8 kr0, kr1, vr0, vr1;
  auto load_kv = [&]() {
    kr0 = *(const bf16x8*)(kg0);
    kr1 = *(const bf16x8*)(kg1);
    vr0 = *(const bf16x8*)(vg0);
    vr1 = *(const bf16x8*)(vg1);
    kg0 += 64 * DH; kg1 += 64 * DH; vg0 += 64; vg1 += 64;
  };

  bf16x8 qf[2];
  {
    const u16* qp = qrot + (bhS + q0 + il) * DH + lg * 8;
    qf[0] = *(const bf16x8*)(qp);
    qf[1] = *(const bf16x8*)(qp + 32);
  }

  float cbv[16];
#pragma unroll
  for (int nt = 0; nt < 4; ++nt)
#pragma unroll
    for (int r = 0; r < 4; ++r)
      cbv[nt * 4 + r] = (float)(nt * 16 + lg * 4 + r) * cdec2;

  f32x4 zero4 = {0.f, 0.f, 0.f, 0.f};
  f32x4 oacc[4];
#pragma unroll
  for (int nt = 0; nt < 4; ++nt) oacc[nt] = zero4;
  float mrun = 0.f, lrun = 0.f;
  float step = 64.f * cdec2;
  float tb = 0.f;

  auto tile = [&](auto Pc, auto Dc) {
    constexpr int P = decltype(Pc)::v;
    constexpr bool DIAG = (decltype(Dc)::v != 0);
    // ---- QK^T with bias as C-init (scores relative to mrun) ----
    float mt = tb - mrun;
    f32x4 sacc[4];
#pragma unroll
    for (int nt = 0; nt < 4; ++nt)
#pragma unroll
      for (int r = 0; r < 4; ++r) sacc[nt][r] = cbv[nt * 4 + r] + mt;
    __builtin_amdgcn_s_setprio(1);
#pragma unroll
    for (int nt = 0; nt < 4; ++nt) {
      bf16x8 kf0 = *(const bf16x8*)(kvb[0] + P * 8192 + nt * 2048);
      bf16x8 kf1 = *(const bf16x8*)(kvb[1] + P * 8192 + nt * 2048);
      sacc[nt] = __builtin_amdgcn_mfma_f32_16x16x32_bf16(kf0, qf[0], sacc[nt], 0, 0, 0);
      sacc[nt] = __builtin_amdgcn_mfma_f32_16x16x32_bf16(kf1, qf[1], sacc[nt], 0, 0, 0);
    }
    __builtin_amdgcn_s_setprio(0);

    float pv[16];
#pragma unroll
    for (int nt = 0; nt < 4; ++nt)
#pragma unroll
      for (int r = 0; r < 4; ++r) {
        float v = sacc[nt][r];
        if (DIAG) {
          int jl = nt * 16 + lg * 4 + r;
          v = (jl <= il) ? v : -1e30f;
        }
        pv[nt * 4 + r] = v;
      }

    // ---- row max (relative to mrun already) ----
    float m1 = pv[0];
#pragma unroll
    for (int i = 1; i < 16; ++i) m1 = fmaxf(m1, pv[i]);
    m1 = fmaxf(m1, __shfl_xor(m1, 16));
    m1 = fmaxf(m1, __shfl_xor(m1, 32));

    // ---- defer-max rescale (THR=8 in log2 units) ----
    if (__ballot(m1 > 8.f)) {
      float d = fmaxf(m1, 0.f);
      float fac = __builtin_amdgcn_exp2f(-d);
      mrun += d;
      lrun *= fac;
      int fi = __float_as_int(fac);
      float facr[4];
#pragma unroll
      for (int r = 0; r < 4; ++r)
        facr[r] = __int_as_float(__builtin_amdgcn_ds_bpermute((4 * lg + r) << 2, fi));
#pragma unroll
      for (int nt = 0; nt < 4; ++nt)
#pragma unroll
        for (int r = 0; r < 4; ++r) oacc[nt][r] *= facr[r];
#pragma unroll
      for (int i = 0; i < 16; ++i) pv[i] -= d;
    }

    // ---- exp2 + row sum ----
    float p[16];
    float rsum = 0.f;
#pragma unroll
    for (int i = 0; i < 16; ++i) {
      p[i] = __builtin_amdgcn_exp2f(pv[i]);
      rsum += p[i];
    }
    rsum += __shfl_xor(rsum, 16);
    rsum += __shfl_xor(rsum, 32);
    lrun += rsum;

    // ---- pack P -> per-wave LDS (precomputed slot bases) ----
#pragma unroll
    for (int nt = 0; nt < 4; ++nt)
#pragma unroll
      for (int rp = 0; rp < 2; ++rp) {
        u32 pk;
        asm("v_cvt_pk_bf16_f32 %0, %1, %2" : "=v"(pk)
            : "v"(p[nt * 4 + 2 * rp]), "v"(p[nt * 4 + 2 * rp + 1]));
        *(u32*)(pw[nt] + rp * 4) = pk;
      }

    // ---- V fragments ----
    bf16x8 vf0[4], vf1[4];
#pragma unroll
    for (int nt = 0; nt < 4; ++nt) {
      vf0[nt] = *(const bf16x8*)(kvb[0] + 16384 + P * 8192 + nt * 2048);
      vf1[nt] = *(const bf16x8*)(kvb[1] + 16384 + P * 8192 + nt * 2048);
    }
    asm volatile("s_waitcnt lgkmcnt(0)" ::: "memory");
    bf16x8 pf0 = *(const bf16x8*)(prd[0]);
    bf16x8 pf1 = *(const bf16x8*)(prd[1]);

    __builtin_amdgcn_s_setprio(1);
#pragma unroll
    for (int nt = 0; nt < 4; ++nt) {
      oacc[nt] = __builtin_amdgcn_mfma_f32_16x16x32_bf16(pf0, vf0[nt], oacc[nt], 0, 0, 0);
      oacc[nt] = __builtin_amdgcn_mfma_f32_16x16x32_bf16(pf1, vf1[nt], oacc[nt], 0, 0, 0);
    }
    __builtin_amdgcn_s_setprio(0);
  };

  auto stage = [&](auto Pc) {
    constexpr int P = decltype(Pc)::v;
    *(bf16x8*)(sp + P * 8192) = kr0;
    *(bf16x8*)(sp + P * 8192 + 4096) = kr1;
    *(bf16x8*)(sp + 16384 + P * 8192) = vr0;
    *(bf16x8*)(sp + 16384 + P * 8192 + 4096) = vr1;
  };

  load_kv();
  int t = 0;
  while (true) {
    stage(IC<0>{});                       // vmcnt wait via dataflow on kr/vr
    if (t < qt) load_kv();                // prefetch stays in flight across barrier
    asm volatile("s_waitcnt lgkmcnt(0)" ::: "memory");
    __builtin_amdgcn_s_barrier();
    if (t == qt) { tile(IC<0>{}, IC<1>{}); break; }
    tile(IC<0>{}, IC<0>{});
    ++t; tb += step;

    stage(IC<1>{});
    if (t < qt) load_kv();
    asm volatile("s_waitcnt lgkmcnt(0)" ::: "memory");
    __builtin_amdgcn_s_barrier();
    if (t == qt) { tile(IC<1>{}, IC<1>{}); break; }
    tile(IC<1>{}, IC<0>{});
    ++t; tb += step;
  }

  // ---- epilogue ----
  float lfin[4], linv[4];
  int li = __float_as_int(lrun);
#pragma unroll
  for (int r = 0; r < 4; ++r) {
    lfin[r] = __int_as_float(__builtin_amdgcn_ds_bpermute((4 * lg + r) << 2, li));
    linv[r] = 1.0f / lfin[r];
  }
#pragma unroll
  for (int nt = 0; nt < 4; ++nt)
#pragma unroll
    for (int r = 0; r < 4; ++r) {
      int srow = q0 + w * 16 + lg * 4 + r;
      int col = h * DH + nt * 16 + lr;
      attnout[((size_t)b * S_LEN + srow) * DM + col] = f2bf(oacc[nt][r] * linv[r]);
    }
}

// ---------------- launch ----------------
extern "C" void kernel_launch(void* const* d_in, const int* in_sizes, int n_in,
                              void* d_out, int out_size, void* d_ws, size_t ws_size,
                              hipStream_t stream) {
  const float* x    = (const float*)d_in[0];
  const float* Wqkv = (const float*)d_in[1];
  const float* Wo   = (const float*)d_in[2];
  const float* log_xi        = (const float*)d_in[3];
  const float* pi_gate_logit = (const float*)d_in[4];
  const float* e_gate_logit  = (const float*)d_in[5];

  u16* xb     = (u16*)d_ws;                 // 4096x1024
  u16* wqkvb  = xb + 4194304;               // 3072x1024
  u16* wob    = wqkvb + 3145728;            // 1024x1024
  u16* qkv    = wob + 1048576;              // 4096x3072
  u16* qrot   = qkv + 12582912;             // 32x2048x64
  u16* krot   = qrot + 4194304;
  u16* vt     = krot + 4194304;             // 32x64x2048
  u16* attno  = vt + 4194304;               // 4096x1024

  conv3_kernel<<<4096, 256, 0, stream>>>(x, Wqkv, Wo, xb, wqkvb, wob);

  gemm_bt<0><<<dim3(24, 32), 256, 0, stream>>>(xb, wqkvb, qkv, 3072, 1024);

  rope_kernel<<<dim3(32, 32), 256, 0, stream>>>(qkv, pi_gate_logit, qrot, krot, vt);

  attn_kernel<<<dim3(32, 32), 256, 0, stream>>>(qrot, krot, vt, log_xi, e_gate_logit, attno);

  gemm_bt<1><<<dim3(8, 32), 256, 0, stream>>>(attno, wob, d_out, 1024, 1024);
}

// Round 7
// 115.271 us; speedup vs baseline: 2.1143x; 2.1143x over previous
//
#include <hip/hip_runtime.h>

typedef unsigned short u16;
typedef unsigned int u32;
typedef __bf16 bf16x8 __attribute__((ext_vector_type(8)));
typedef float f32x4 __attribute__((ext_vector_type(4)));
typedef u16 u16x4 __attribute__((ext_vector_type(4)));

#define S_LEN 2048
#define NH 16
#define DH 64
#define DM 1024

#define GLDS(gp, lp) __builtin_amdgcn_global_load_lds( \
    (const __attribute__((address_space(1))) void*)(gp), \
    (__attribute__((address_space(3))) void*)(lp), 16, 0, 0)

__device__ __forceinline__ u16 f2bf(float f) {
  unsigned u = __float_as_uint(f);
  u += 0x7FFFu + ((u >> 16) & 1u);
  return (u16)(u >> 16);
}
__device__ __forceinline__ float bf2f(u16 h) {
  return __uint_as_float(((unsigned)h) << 16);
}

// ---------------- convert f32 -> bf16 (x, Wqkv, Wo in one launch) ----------------
__global__ __launch_bounds__(256) void conv3_kernel(const float* __restrict__ a,
                                                    const float* __restrict__ wb,
                                                    const float* __restrict__ wc,
                                                    u16* __restrict__ oa,
                                                    u16* __restrict__ ob,
                                                    u16* __restrict__ oc) {
  int bid = blockIdx.x;
  const float* in;
  u16* out;
  int idx;
  if (bid < 2048)      { in = a;  out = oa; idx = bid; }
  else if (bid < 3584) { in = wb; out = ob; idx = bid - 2048; }
  else                 { in = wc; out = oc; idx = bid - 3584; }
  int i = idx * 2048 + threadIdx.x * 8;
  float4 v0 = *(const float4*)(in + i);
  float4 v1 = *(const float4*)(in + i + 4);
  u16x4 o0, o1;
  o0.x = f2bf(v0.x); o0.y = f2bf(v0.y); o0.z = f2bf(v0.z); o0.w = f2bf(v0.w);
  o1.x = f2bf(v1.x); o1.y = f2bf(v1.y); o1.z = f2bf(v1.z); o1.w = f2bf(v1.w);
  *(u16x4*)(out + i) = o0;
  *(u16x4*)(out + i + 4) = o1;
}

// ---------------- bf16 GEMM: C[M][N] = A[M][K] * B[N][K]^T ----------------
// 128x128 tile, BK=32, 4 waves, 2-phase double-buffered global_load_lds:
// stage(t+1) issued before compute(t); single vmcnt(0)+s_barrier per K-step.
template <int OUTF32>
__global__ __launch_bounds__(256) void gemm_bt(const u16* __restrict__ A,
                                               const u16* __restrict__ B,
                                               void* __restrict__ C,
                                               int N, int K) {
  __shared__ __align__(16) u16 smem[16384];  // 2 bufs x (A 4096 + B 4096)
  int tid = threadIdx.x;
  int w = tid >> 6, l = tid & 63, lg = l >> 4, lr = l & 15;
  int m0 = blockIdx.y * 128, n0 = blockIdx.x * 128;
  int wm = (w >> 1) * 64, wn = (w & 1) * 64;
  int NK = K >> 5;

  int srow0 = w * 16 + (l >> 2);
  int srow1 = srow0 + 64;
  int scol = (l & 3) * 8;
  const u16* gA0 = A + (size_t)(m0 + srow0) * K + scol;
  const u16* gA1 = A + (size_t)(m0 + srow1) * K + scol;
  const u16* gB0 = B + (size_t)(n0 + srow0) * K + scol;
  const u16* gB1 = B + (size_t)(n0 + srow1) * K + scol;

  auto stage = [&](int p) {
    u16* ab = smem + p * 8192;
    u16* bb = ab + 4096;
    GLDS(gA0, ab + w * 512);
    GLDS(gA1, ab + (4 + w) * 512);
    GLDS(gB0, bb + w * 512);
    GLDS(gB1, bb + (4 + w) * 512);
  };
  auto adv = [&]() { gA0 += 32; gA1 += 32; gB0 += 32; gB1 += 32; };

  f32x4 zero4 = {0.f, 0.f, 0.f, 0.f};
  f32x4 acc[4][4];
#pragma unroll
  for (int mt = 0; mt < 4; ++mt)
#pragma unroll
    for (int nt = 0; nt < 4; ++nt) acc[mt][nt] = zero4;

  stage(0);
  adv();
  __syncthreads();  // prologue: full drain ok

  int p = 0;
  for (int kt = 0; kt < NK; ++kt) {
    bool pre = (kt + 1 < NK);
    if (pre) { stage(p ^ 1); adv(); }

    const u16* ab = smem + p * 8192;
    const u16* bb = ab + 4096;
    bf16x8 af[4], bfr[4];
#pragma unroll
    for (int mt = 0; mt < 4; ++mt)
      af[mt] = *(const bf16x8*)(ab + (wm + mt * 16 + lr) * 32 + lg * 8);
#pragma unroll
    for (int nt = 0; nt < 4; ++nt)
      bfr[nt] = *(const bf16x8*)(bb + (wn + nt * 16 + lr) * 32 + lg * 8);
    __builtin_amdgcn_s_setprio(1);
#pragma unroll
    for (int mt = 0; mt < 4; ++mt)
#pragma unroll
      for (int nt = 0; nt < 4; ++nt)
        acc[mt][nt] = __builtin_amdgcn_mfma_f32_16x16x32_bf16(af[mt], bfr[nt], acc[mt][nt], 0, 0, 0);
    __builtin_amdgcn_s_setprio(0);

    if (pre) {
      asm volatile("s_waitcnt vmcnt(0)" ::: "memory");
      __builtin_amdgcn_s_barrier();
    }
    p ^= 1;
  }

#pragma unroll
  for (int mt = 0; mt < 4; ++mt)
#pragma unroll
    for (int nt = 0; nt < 4; ++nt)
#pragma unroll
      for (int r = 0; r < 4; ++r) {
        int row = m0 + wm + mt * 16 + lg * 4 + r;
        int col = n0 + wn + nt * 16 + lr;
        float v = acc[mt][nt][r];
        if (OUTF32) ((float*)C)[(size_t)row * N + col] = v;
        else        ((u16*)C)[(size_t)row * N + col] = f2bf(v);
      }
}

// ---------------- RoPE + head-major layout + V transpose ----------------
// Q is pre-scaled by 1/sqrt(dh) = 0.125 here.
__global__ __launch_bounds__(256) void rope_kernel(const u16* __restrict__ qkv,
                                                   const float* __restrict__ pi_gate_logit,
                                                   u16* __restrict__ qrot,
                                                   u16* __restrict__ krot,
                                                   u16* __restrict__ vt) {
  int st = blockIdx.x;   // s tile (0..31)
  int bh = blockIdx.y;   // b*16+h
  int h = bh & 15;
  int t = threadIdx.x;
  int sl = t >> 2;       // 0..63
  int pb = t & 3;
  int d0 = pb * 16;
  int s = st * 64 + sl;
  int b = bh >> 4;
  size_t rowg = (size_t)(b * S_LEN + s) * (3 * DM) + h * DH + d0;

  float pg = 1.0f / (1.0f + __expf(-pi_gate_logit[h]));
  float spos = (float)s;
  float cs[8], sn[8];
#pragma unroll
  for (int j = 0; j < 8; ++j) {
    float p = (float)(pb * 8 + j);
    float fr = exp2f((1.0f - p * 0.03125f) * 1.6514961294723187f);  // pi^(1-p/32)
    float th = (spos * fr) * pg;
    float rev = th * 0.15915494309189535f;
    rev = rev - floorf(rev);
    cs[j] = __builtin_amdgcn_cosf(rev);
    sn[j] = __builtin_amdgcn_sinf(rev);
  }

#pragma unroll
  for (int which = 0; which < 2; ++which) {
    const u16* src = qkv + rowg + (size_t)which * DM;
    float sc = which ? 1.0f : 0.125f;
    u16 in[16], ou[16];
    *(bf16x8*)(in)     = *(const bf16x8*)(src);
    *(bf16x8*)(in + 8) = *(const bf16x8*)(src + 8);
#pragma unroll
    for (int j = 0; j < 8; ++j) {
      float t1 = bf2f(in[2 * j]), t2 = bf2f(in[2 * j + 1]);
      ou[2 * j]     = f2bf((t1 * cs[j] - t2 * sn[j]) * sc);
      ou[2 * j + 1] = f2bf((t1 * sn[j] + t2 * cs[j]) * sc);
    }
    u16* dst = (which ? krot : qrot) + ((size_t)bh * S_LEN + s) * DH + d0;
    *(bf16x8*)(dst)     = *(bf16x8*)(ou);
    *(bf16x8*)(dst + 8) = *(bf16x8*)(ou + 8);
  }

  {
    const u16* src = qkv + rowg + 2 * DM;
    u16 in[16];
    *(bf16x8*)(in)     = *(const bf16x8*)(src);
    *(bf16x8*)(in + 8) = *(const bf16x8*)(src + 8);
#pragma unroll
    for (int e = 0; e < 16; ++e)
      vt[((size_t)bh * DH + d0 + e) * S_LEN + st * 64 + sl] = in[e];
  }
}

// ---------------- flash attention tile compute (static indexing) ----------------
// Swapped QK^T: sacc[nt][r] = S^T[kv=nt*16+lg*4+r][q=w*16+lr].
template <bool DIAG>
__device__ __forceinline__ void attn_tile(const unsigned char* __restrict__ kbuf,
                                          const unsigned char* __restrict__ vbuf,
                                          float tb, float cdec,
                                          const bf16x8 (&qf)[2],
                                          f32x4 (&oacc)[4],
                                          float& mrun, float& lrun,
                                          int lg, int lr, int il,
                                          unsigned char* pbuf) {
  f32x4 zero4 = {0.f, 0.f, 0.f, 0.f};

  // ---- QK^T from LDS ----
  f32x4 sacc[4];
#pragma unroll
  for (int nt = 0; nt < 4; ++nt) sacc[nt] = zero4;
  __builtin_amdgcn_s_setprio(1);
#pragma unroll
  for (int nt = 0; nt < 4; ++nt)
#pragma unroll
    for (int kk = 0; kk < 2; ++kk) {
      int row = nt * 16 + lr;
      int sl_ = lg + kk * 4;
      bf16x8 kf = *(const bf16x8*)(kbuf + row * 128 + ((sl_ ^ (row & 7)) << 4));
      sacc[nt] = __builtin_amdgcn_mfma_f32_16x16x32_bf16(kf, qf[kk], sacc[nt], 0, 0, 0);
    }
  __builtin_amdgcn_s_setprio(0);

  // ---- scores + bias (+ causal mask on diagonal) ----
  float pv[16];
  float base = tb + (float)(lg * 4) * cdec;
#pragma unroll
  for (int nt = 0; nt < 4; ++nt)
#pragma unroll
    for (int r = 0; r < 4; ++r) {
      float v = sacc[nt][r] + fmaf((float)(nt * 16 + r), cdec, base);
      if (DIAG) {
        int jl = nt * 16 + lg * 4 + r;
        v = (jl <= il) ? v : -1e30f;
      }
      pv[nt * 4 + r] = v;
    }

  // ---- row max: in-lane tree + 2 shuffles ----
  float m1 = pv[0];
#pragma unroll
  for (int i = 1; i < 16; ++i) m1 = fmaxf(m1, pv[i]);
  m1 = fmaxf(m1, __shfl_xor(m1, 16));
  m1 = fmaxf(m1, __shfl_xor(m1, 32));

  // ---- defer-max rescale (THR=8) ----
  if (__ballot(m1 > mrun + 8.f)) {
    float mnew = fmaxf(mrun, m1);
    float fac = __expf(mrun - mnew);
    mrun = mnew;
    lrun *= fac;
    int fi = __float_as_int(fac);
    float facr[4];
#pragma unroll
    for (int r = 0; r < 4; ++r)
      facr[r] = __int_as_float(__builtin_amdgcn_ds_bpermute((4 * lg + r) << 2, fi));
#pragma unroll
    for (int nt = 0; nt < 4; ++nt)
#pragma unroll
      for (int r = 0; r < 4; ++r) oacc[nt][r] *= facr[r];
  }

  // ---- exp + row sum ----
  float p[16];
  float rsum = 0.f;
#pragma unroll
  for (int i = 0; i < 16; ++i) {
    p[i] = __expf(pv[i] - mrun);
    rsum += p[i];
  }
  rsum += __shfl_xor(rsum, 16);
  rsum += __shfl_xor(rsum, 32);
  lrun += rsum;

  // ---- pack P -> per-wave swizzled LDS -> A-fragments ----
#pragma unroll
  for (int nt = 0; nt < 4; ++nt)
#pragma unroll
    for (int rp = 0; rp < 2; ++rp) {
      u32 pk;
      asm("v_cvt_pk_bf16_f32 %0, %1, %2" : "=v"(pk)
          : "v"(p[nt * 4 + 2 * rp]), "v"(p[nt * 4 + 2 * rp + 1]));
      *(u32*)(pbuf + ((lr * 128 + nt * 32 + lg * 8 + rp * 4) ^ ((lr & 7) << 4))) = pk;
    }
  asm volatile("s_waitcnt lgkmcnt(0)" ::: "memory");

  bf16x8 pf[2];
#pragma unroll
  for (int kk = 0; kk < 2; ++kk)
    pf[kk] = *(const bf16x8*)(pbuf + ((lr * 128 + (lg + 4 * kk) * 16) ^ ((lr & 7) << 4)));

  // ---- PV from LDS ----
  __builtin_amdgcn_s_setprio(1);
#pragma unroll
  for (int nt = 0; nt < 4; ++nt)
#pragma unroll
    for (int kk = 0; kk < 2; ++kk) {
      int row = nt * 16 + lr;
      int sl_ = lg + kk * 4;
      bf16x8 vf = *(const bf16x8*)(vbuf + row * 128 + ((sl_ ^ (row & 7)) << 4));
      oacc[nt] = __builtin_amdgcn_mfma_f32_16x16x32_bf16(pf[kk], vf, oacc[nt], 0, 0, 0);
    }
  __builtin_amdgcn_s_setprio(0);
}

// Flash attention: double-buffered LDS K/V (ONE barrier per tile), reg
// prefetch one tile ahead, heavy-first grid (qt = 31 - blockIdx.y).
__global__ __launch_bounds__(256, 3) void attn_kernel(const u16* __restrict__ qrot,
                                                      const u16* __restrict__ krot,
                                                      const u16* __restrict__ vt,
                                                      const float* __restrict__ log_xi,
                                                      const float* __restrict__ e_gate_logit,
                                                      u16* __restrict__ attnout) {
  int bh = blockIdx.x;
  int qt = 31 - blockIdx.y;
  int b = bh >> 4, h = bh & 15;
  int tid = threadIdx.x, w = tid >> 6, l = tid & 63, lg = l >> 4, lr = l & 15;
  int q0 = qt * 64;
  int il = w * 16 + lr;  // this lane's q-row, local to the 64-row tile

  float eg = 1.0f / (1.0f + __expf(-e_gate_logit[h]));
  float cdec = eg * __expf(-log_xi[h]);  // e_g / xi

  __shared__ __align__(16) unsigned char smem[40960];
  // [0:16384) kbuf[2], [16384:32768) vbuf[2], [32768:40960) pbuf per-wave
  unsigned char* pbuf = smem + 32768 + (w << 11);

  const size_t bhS = (size_t)bh * S_LEN;
  const u16* kb0 = krot + bhS * DH;
  const u16* vb0 = vt + (size_t)bh * DH * S_LEN;

  bf16x8 qf[2];
  {
    const u16* qp = qrot + (bhS + q0 + il) * DH + lg * 8;
    qf[0] = *(const bf16x8*)(qp);
    qf[1] = *(const bf16x8*)(qp + 32);
  }

  // staging geometry: 512 chunks of 16B per 8KB tile; this thread's 2 chunks
  int c0 = tid, c1 = 256 + tid;
  int row0 = c0 >> 3, sl0 = c0 & 7;
  int row1 = c1 >> 3, sl1 = c1 & 7;

  bf16x8 kr[2], vr[2];
  auto load_kv = [&](int t) {
    kr[0] = *(const bf16x8*)(kb0 + (size_t)(t * 64 + row0) * DH + sl0 * 8);
    kr[1] = *(const bf16x8*)(kb0 + (size_t)(t * 64 + row1) * DH + sl1 * 8);
    vr[0] = *(const bf16x8*)(vb0 + (size_t)row0 * S_LEN + t * 64 + sl0 * 8);
    vr[1] = *(const bf16x8*)(vb0 + (size_t)row1 * S_LEN + t * 64 + sl1 * 8);
  };
  auto stage = [&](int p) {
    unsigned char* kb = smem + p * 8192;
    unsigned char* vb = smem + 16384 + p * 8192;
    *(bf16x8*)(kb + row0 * 128 + ((sl0 ^ (row0 & 7)) << 4)) = kr[0];
    *(bf16x8*)(kb + row1 * 128 + ((sl1 ^ (row1 & 7)) << 4)) = kr[1];
    *(bf16x8*)(vb + row0 * 128 + ((sl0 ^ (row0 & 7)) << 4)) = vr[0];
    *(bf16x8*)(vb + row1 * 128 + ((sl1 ^ (row1 & 7)) << 4)) = vr[1];
  };

  f32x4 zero4 = {0.f, 0.f, 0.f, 0.f};
  f32x4 oacc[4];
#pragma unroll
  for (int nt = 0; nt < 4; ++nt) oacc[nt] = zero4;
  float mrun = -1e30f, lrun = 0.f;

  load_kv(0);
  float step = 64.f * cdec;
  float tb = 0.f;
  int p = 0;
  for (int t = 0; t < qt; ++t, tb += step, p ^= 1) {
    stage(p);           // waits vmcnt for kr/vr internally
    load_kv(t + 1);     // prefetch next tile; drains at next stage()
    __syncthreads();    // staged writes visible; prev buffer's readers done
    attn_tile<false>(smem + p * 8192, smem + 16384 + p * 8192, tb, cdec,
                     qf, oacc, mrun, lrun, lg, lr, il, pbuf);
  }
  stage(p);
  __syncthreads();
  attn_tile<true>(smem + p * 8192, smem + 16384 + p * 8192, tb, cdec,
                  qf, oacc, mrun, lrun, lg, lr, il, pbuf);

  // ---- epilogue: redistribute l (lane p in 0..15 holds q-row p's sum) ----
  float lfin[4];
  int li = __float_as_int(lrun);
#pragma unroll
  for (int r = 0; r < 4; ++r)
    lfin[r] = __int_as_float(__builtin_amdgcn_ds_bpermute((4 * lg + r) << 2, li));
#pragma unroll
  for (int nt = 0; nt < 4; ++nt)
#pragma unroll
    for (int r = 0; r < 4; ++r) {
      int srow = q0 + w * 16 + lg * 4 + r;
      int col = h * DH + nt * 16 + lr;
      attnout[((size_t)b * S_LEN + srow) * DM + col] = f2bf(oacc[nt][r] / lfin[r]);
    }
}

// ---------------- launch ----------------
extern "C" void kernel_launch(void* const* d_in, const int* in_sizes, int n_in,
                              void* d_out, int out_size, void* d_ws, size_t ws_size,
                              hipStream_t stream) {
  const float* x    = (const float*)d_in[0];
  const float* Wqkv = (const float*)d_in[1];
  const float* Wo   = (const float*)d_in[2];
  const float* log_xi        = (const float*)d_in[3];
  const float* pi_gate_logit = (const float*)d_in[4];
  const float* e_gate_logit  = (const float*)d_in[5];

  u16* xb     = (u16*)d_ws;                 // 4096x1024
  u16* wqkvb  = xb + 4194304;               // 3072x1024
  u16* wob    = wqkvb + 3145728;            // 1024x1024
  u16* qkv    = wob + 1048576;              // 4096x3072
  u16* qrot   = qkv + 12582912;             // 32x2048x64
  u16* krot   = qrot + 4194304;
  u16* vt     = krot + 4194304;             // 32x64x2048
  u16* attno  = vt + 4194304;               // 4096x1024

  conv3_kernel<<<4096, 256, 0, stream>>>(x, Wqkv, Wo, xb, wqkvb, wob);

  gemm_bt<0><<<dim3(24, 32), 256, 0, stream>>>(xb, wqkvb, qkv, 3072, 1024);

  rope_kernel<<<dim3(32, 32), 256, 0, stream>>>(qkv, pi_gate_logit, qrot, krot, vt);

  attn_kernel<<<dim3(32, 32), 256, 0, stream>>>(qrot, krot, vt, log_xi, e_gate_logit, attno);

  gemm_bt<1><<<dim3(8, 32), 256, 0, stream>>>(attno, wob, d_out, 1024, 1024);
}

// Round 9
// 112.339 us; speedup vs baseline: 2.1695x; 1.0261x over previous
//
#include <hip/hip_runtime.h>

typedef unsigned short u16;
typedef unsigned int u32;
typedef __bf16 bf16x8 __attribute__((ext_vector_type(8)));
typedef float f32x4 __attribute__((ext_vector_type(4)));
typedef u16 u16x4 __attribute__((ext_vector_type(4)));

#define S_LEN 2048
#define NH 16
#define DH 64
#define DM 1024

#define GLDS(gp, lp) __builtin_amdgcn_global_load_lds( \
    (const __attribute__((address_space(1))) void*)(gp), \
    (__attribute__((address_space(3))) void*)(lp), 16, 0, 0)

__device__ __forceinline__ u16 f2bf(float f) {
  unsigned u = __float_as_uint(f);
  u += 0x7FFFu + ((u >> 16) & 1u);
  return (u16)(u >> 16);
}
__device__ __forceinline__ float bf2f(u16 h) {
  return __uint_as_float(((unsigned)h) << 16);
}

// ---------------- convert f32 -> bf16 (x, Wqkv, Wo in one launch) ----------------
__global__ __launch_bounds__(256) void conv3_kernel(const float* __restrict__ a,
                                                    const float* __restrict__ wb,
                                                    const float* __restrict__ wc,
                                                    u16* __restrict__ oa,
                                                    u16* __restrict__ ob,
                                                    u16* __restrict__ oc) {
  int bid = blockIdx.x;
  const float* in;
  u16* out;
  int idx;
  if (bid < 2048)      { in = a;  out = oa; idx = bid; }
  else if (bid < 3584) { in = wb; out = ob; idx = bid - 2048; }
  else                 { in = wc; out = oc; idx = bid - 3584; }
  int i = idx * 2048 + threadIdx.x * 8;
  float4 v0 = *(const float4*)(in + i);
  float4 v1 = *(const float4*)(in + i + 4);
  u16x4 o0, o1;
  o0.x = f2bf(v0.x); o0.y = f2bf(v0.y); o0.z = f2bf(v0.z); o0.w = f2bf(v0.w);
  o1.x = f2bf(v1.x); o1.y = f2bf(v1.y); o1.z = f2bf(v1.z); o1.w = f2bf(v1.w);
  *(u16x4*)(out + i) = o0;
  *(u16x4*)(out + i + 4) = o1;
}

// ---------------- bf16 GEMM: C[M][N] = A[M][K] * B[N][K]^T ----------------
// 128x128 tile, BK=32, 4 waves, 2-phase double-buffered global_load_lds:
// stage(t+1) issued before compute(t); single vmcnt(0)+s_barrier per K-step.
template <int OUTF32>
__global__ __launch_bounds__(256) void gemm_bt(const u16* __restrict__ A,
                                               const u16* __restrict__ B,
                                               void* __restrict__ C,
                                               int N, int K) {
  __shared__ __align__(16) u16 smem[16384];  // 2 bufs x (A 4096 + B 4096)
  int tid = threadIdx.x;
  int w = tid >> 6, l = tid & 63, lg = l >> 4, lr = l & 15;
  int m0 = blockIdx.y * 128, n0 = blockIdx.x * 128;
  int wm = (w >> 1) * 64, wn = (w & 1) * 64;
  int NK = K >> 5;

  int srow0 = w * 16 + (l >> 2);
  int srow1 = srow0 + 64;
  int scol = (l & 3) * 8;
  const u16* gA0 = A + (size_t)(m0 + srow0) * K + scol;
  const u16* gA1 = A + (size_t)(m0 + srow1) * K + scol;
  const u16* gB0 = B + (size_t)(n0 + srow0) * K + scol;
  const u16* gB1 = B + (size_t)(n0 + srow1) * K + scol;

  auto stage = [&](int p) {
    u16* ab = smem + p * 8192;
    u16* bb = ab + 4096;
    GLDS(gA0, ab + w * 512);
    GLDS(gA1, ab + (4 + w) * 512);
    GLDS(gB0, bb + w * 512);
    GLDS(gB1, bb + (4 + w) * 512);
  };
  auto adv = [&]() { gA0 += 32; gA1 += 32; gB0 += 32; gB1 += 32; };

  f32x4 zero4 = {0.f, 0.f, 0.f, 0.f};
  f32x4 acc[4][4];
#pragma unroll
  for (int mt = 0; mt < 4; ++mt)
#pragma unroll
    for (int nt = 0; nt < 4; ++nt) acc[mt][nt] = zero4;

  stage(0);
  adv();
  __syncthreads();  // prologue: full drain ok

  int p = 0;
  for (int kt = 0; kt < NK; ++kt) {
    bool pre = (kt + 1 < NK);
    if (pre) { stage(p ^ 1); adv(); }

    const u16* ab = smem + p * 8192;
    const u16* bb = ab + 4096;
    bf16x8 af[4], bfr[4];
#pragma unroll
    for (int mt = 0; mt < 4; ++mt)
      af[mt] = *(const bf16x8*)(ab + (wm + mt * 16 + lr) * 32 + lg * 8);
#pragma unroll
    for (int nt = 0; nt < 4; ++nt)
      bfr[nt] = *(const bf16x8*)(bb + (wn + nt * 16 + lr) * 32 + lg * 8);
    __builtin_amdgcn_s_setprio(1);
#pragma unroll
    for (int mt = 0; mt < 4; ++mt)
#pragma unroll
      for (int nt = 0; nt < 4; ++nt)
        acc[mt][nt] = __builtin_amdgcn_mfma_f32_16x16x32_bf16(af[mt], bfr[nt], acc[mt][nt], 0, 0, 0);
    __builtin_amdgcn_s_setprio(0);

    if (pre) {
      asm volatile("s_waitcnt vmcnt(0)" ::: "memory");
      __builtin_amdgcn_s_barrier();
    }
    p ^= 1;
  }

#pragma unroll
  for (int mt = 0; mt < 4; ++mt)
#pragma unroll
    for (int nt = 0; nt < 4; ++nt)
#pragma unroll
      for (int r = 0; r < 4; ++r) {
        int row = m0 + wm + mt * 16 + lg * 4 + r;
        int col = n0 + wn + nt * 16 + lr;
        float v = acc[mt][nt][r];
        if (OUTF32) ((float*)C)[(size_t)row * N + col] = v;
        else        ((u16*)C)[(size_t)row * N + col] = f2bf(v);
      }
}

// ---------------- RoPE + head-major layout + V transpose ----------------
// Q is pre-scaled by (1/sqrt(dh)) * log2(e) (attn softmax runs in exp2 domain).
__global__ __launch_bounds__(256) void rope_kernel(const u16* __restrict__ qkv,
                                                   const float* __restrict__ pi_gate_logit,
                                                   u16* __restrict__ qrot,
                                                   u16* __restrict__ krot,
                                                   u16* __restrict__ vt) {
  int st = blockIdx.x;   // s tile (0..31)
  int bh = blockIdx.y;   // b*16+h
  int h = bh & 15;
  int t = threadIdx.x;
  int sl = t >> 2;       // 0..63
  int pb = t & 3;
  int d0 = pb * 16;
  int s = st * 64 + sl;
  int b = bh >> 4;
  size_t rowg = (size_t)(b * S_LEN + s) * (3 * DM) + h * DH + d0;

  float pg = 1.0f / (1.0f + __expf(-pi_gate_logit[h]));
  float spos = (float)s;
  float cs[8], sn[8];
#pragma unroll
  for (int j = 0; j < 8; ++j) {
    float p = (float)(pb * 8 + j);
    float fr = exp2f((1.0f - p * 0.03125f) * 1.6514961294723187f);  // pi^(1-p/32)
    float th = (spos * fr) * pg;
    float rev = th * 0.15915494309189535f;
    rev = rev - floorf(rev);
    cs[j] = __builtin_amdgcn_cosf(rev);
    sn[j] = __builtin_amdgcn_sinf(rev);
  }

#pragma unroll
  for (int which = 0; which < 2; ++which) {
    const u16* src = qkv + rowg + (size_t)which * DM;
    float sc = which ? 1.0f : 0.18033688011111772f;  // 0.125 * log2(e)
    u16 in[16], ou[16];
    *(bf16x8*)(in)     = *(const bf16x8*)(src);
    *(bf16x8*)(in + 8) = *(const bf16x8*)(src + 8);
#pragma unroll
    for (int j = 0; j < 8; ++j) {
      float t1 = bf2f(in[2 * j]), t2 = bf2f(in[2 * j + 1]);
      ou[2 * j]     = f2bf((t1 * cs[j] - t2 * sn[j]) * sc);
      ou[2 * j + 1] = f2bf((t1 * sn[j] + t2 * cs[j]) * sc);
    }
    u16* dst = (which ? krot : qrot) + ((size_t)bh * S_LEN + s) * DH + d0;
    *(bf16x8*)(dst)     = *(bf16x8*)(ou);
    *(bf16x8*)(dst + 8) = *(bf16x8*)(ou + 8);
  }

  {
    const u16* src = qkv + rowg + 2 * DM;
    u16 in[16];
    *(bf16x8*)(in)     = *(const bf16x8*)(src);
    *(bf16x8*)(in + 8) = *(const bf16x8*)(src + 8);
#pragma unroll
    for (int e = 0; e < 16; ++e)
      vt[((size_t)bh * DH + d0 + e) * S_LEN + st * 64 + sl] = in[e];
  }
}

// ---------------- flash attention tile compute (static indexing) ----------------
// Swapped QK^T: sacc[nt][r] = S^T[kv=nt*16+lg*4+r][q=w*16+lr].
// exp2-domain; decay bias + (tb - mrun) folded into MFMA C-init (r6-validated
// math); lrun/row-sum via shuffles (r7-validated structure). No ones-MFMA.
template <bool DIAG>
__device__ __forceinline__ void attn_tile(const unsigned char* __restrict__ kbuf,
                                          const unsigned char* __restrict__ vbuf,
                                          float mt, const float (&cbv)[16],
                                          const bf16x8 (&qf)[2],
                                          f32x4 (&oacc)[4],
                                          float& mrun, float& lrun,
                                          int lg, int lr, int il,
                                          unsigned char* pbuf) {
  // ---- QK^T with C-init = column bias + (tb - mrun) ----
  f32x4 sacc[4];
#pragma unroll
  for (int nt = 0; nt < 4; ++nt)
#pragma unroll
    for (int r = 0; r < 4; ++r) sacc[nt][r] = cbv[nt * 4 + r] + mt;
  __builtin_amdgcn_s_setprio(1);
#pragma unroll
  for (int nt = 0; nt < 4; ++nt)
#pragma unroll
    for (int kk = 0; kk < 2; ++kk) {
      int row = nt * 16 + lr;
      int sl_ = lg + kk * 4;
      bf16x8 kf = *(const bf16x8*)(kbuf + row * 128 + ((sl_ ^ (row & 7)) << 4));
      sacc[nt] = __builtin_amdgcn_mfma_f32_16x16x32_bf16(kf, qf[kk], sacc[nt], 0, 0, 0);
    }
  __builtin_amdgcn_s_setprio(0);

  // ---- (diagonal) causal mask ----
  float pv[16];
#pragma unroll
  for (int nt = 0; nt < 4; ++nt)
#pragma unroll
    for (int r = 0; r < 4; ++r) {
      float v = sacc[nt][r];
      if (DIAG) {
        int jl = nt * 16 + lg * 4 + r;
        v = (jl <= il) ? v : -1e30f;
      }
      pv[nt * 4 + r] = v;
    }

  // ---- row max (relative to mrun): in-lane tree + 2 shuffles ----
  float m1 = pv[0];
#pragma unroll
  for (int i = 1; i < 16; ++i) m1 = fmaxf(m1, pv[i]);
  m1 = fmaxf(m1, __shfl_xor(m1, 16));
  m1 = fmaxf(m1, __shfl_xor(m1, 32));

  // ---- defer-max rescale (THR=8 in log2 units) ----
  if (__ballot(m1 > 8.f)) {
    float d = fmaxf(m1, 0.f);
    float fac = __builtin_amdgcn_exp2f(-d);
    mrun += d;
    lrun *= fac;
    int fi = __float_as_int(fac);
    float facr[4];
#pragma unroll
    for (int r = 0; r < 4; ++r)
      facr[r] = __int_as_float(__builtin_amdgcn_ds_bpermute((4 * lg + r) << 2, fi));
#pragma unroll
    for (int nt = 0; nt < 4; ++nt)
#pragma unroll
      for (int r = 0; r < 4; ++r) oacc[nt][r] *= facr[r];
#pragma unroll
    for (int i = 0; i < 16; ++i) pv[i] -= d;
  }

  // ---- exp2 + row sum ----
  float p[16];
  float rsum = 0.f;
#pragma unroll
  for (int i = 0; i < 16; ++i) {
    p[i] = __builtin_amdgcn_exp2f(pv[i]);
    rsum += p[i];
  }
  rsum += __shfl_xor(rsum, 16);
  rsum += __shfl_xor(rsum, 32);
  lrun += rsum;

  // ---- pack P -> per-wave swizzled LDS -> A-fragments ----
#pragma unroll
  for (int nt = 0; nt < 4; ++nt)
#pragma unroll
    for (int rp = 0; rp < 2; ++rp) {
      u32 pk;
      asm("v_cvt_pk_bf16_f32 %0, %1, %2" : "=v"(pk)
          : "v"(p[nt * 4 + 2 * rp]), "v"(p[nt * 4 + 2 * rp + 1]));
      *(u32*)(pbuf + ((lr * 128 + nt * 32 + lg * 8 + rp * 4) ^ ((lr & 7) << 4))) = pk;
    }
  asm volatile("s_waitcnt lgkmcnt(0)" ::: "memory");

  bf16x8 pf[2];
#pragma unroll
  for (int kk = 0; kk < 2; ++kk)
    pf[kk] = *(const bf16x8*)(pbuf + ((lr * 128 + (lg + 4 * kk) * 16) ^ ((lr & 7) << 4)));

  // ---- PV from LDS ----
  __builtin_amdgcn_s_setprio(1);
#pragma unroll
  for (int nt = 0; nt < 4; ++nt)
#pragma unroll
    for (int kk = 0; kk < 2; ++kk) {
      int row = nt * 16 + lr;
      int sl_ = lg + kk * 4;
      bf16x8 vf = *(const bf16x8*)(vbuf + row * 128 + ((sl_ ^ (row & 7)) << 4));
      oacc[nt] = __builtin_amdgcn_mfma_f32_16x16x32_bf16(pf[kk], vf, oacc[nt], 0, 0, 0);
    }
  __builtin_amdgcn_s_setprio(0);
}

// Flash attention: double-buffered LDS K/V (ONE barrier per tile), reg
// prefetch one tile ahead, heavy-first grid (qt = 31 - blockIdx.y).
__global__ __launch_bounds__(256, 3) void attn_kernel(const u16* __restrict__ qrot,
                                                      const u16* __restrict__ krot,
                                                      const u16* __restrict__ vt,
                                                      const float* __restrict__ log_xi,
                                                      const float* __restrict__ e_gate_logit,
                                                      u16* __restrict__ attnout) {
  int bh = blockIdx.x;
  int qt = 31 - blockIdx.y;
  int b = bh >> 4, h = bh & 15;
  int tid = threadIdx.x, w = tid >> 6, l = tid & 63, lg = l >> 4, lr = l & 15;
  int q0 = qt * 64;
  int il = w * 16 + lr;  // this lane's q-row, local to the 64-row tile

  const float L2E = 1.4426950408889634f;
  float eg = 1.0f / (1.0f + __expf(-e_gate_logit[h]));
  float cdec2 = eg * __expf(-log_xi[h]) * L2E;  // (e_g/xi) * log2e

  __shared__ __align__(16) unsigned char smem[40960];
  // [0:16384) kbuf[2], [16384:32768) vbuf[2], [32768:40960) pbuf per-wave
  unsigned char* pbuf = smem + 32768 + (w << 11);

  const size_t bhS = (size_t)bh * S_LEN;
  const u16* kb0 = krot + bhS * DH;
  const u16* vb0 = vt + (size_t)bh * DH * S_LEN;

  bf16x8 qf[2];
  {
    const u16* qp = qrot + (bhS + q0 + il) * DH + lg * 8;
    qf[0] = *(const bf16x8*)(qp);
    qf[1] = *(const bf16x8*)(qp + 32);
  }

  float cbv[16];
#pragma unroll
  for (int nt = 0; nt < 4; ++nt)
#pragma unroll
    for (int r = 0; r < 4; ++r)
      cbv[nt * 4 + r] = (float)(nt * 16 + lg * 4 + r) * cdec2;

  // staging geometry: 512 chunks of 16B per 8KB tile; this thread's 2 chunks
  int c0 = tid, c1 = 256 + tid;
  int row0 = c0 >> 3, sl0 = c0 & 7;
  int row1 = c1 >> 3, sl1 = c1 & 7;

  bf16x8 kr[2], vr[2];
  auto load_kv = [&](int t) {
    kr[0] = *(const bf16x8*)(kb0 + (size_t)(t * 64 + row0) * DH + sl0 * 8);
    kr[1] = *(const bf16x8*)(kb0 + (size_t)(t * 64 + row1) * DH + sl1 * 8);
    vr[0] = *(const bf16x8*)(vb0 + (size_t)row0 * S_LEN + t * 64 + sl0 * 8);
    vr[1] = *(const bf16x8*)(vb0 + (size_t)row1 * S_LEN + t * 64 + sl1 * 8);
  };
  auto stage = [&](int p) {
    unsigned char* kb = smem + p * 8192;
    unsigned char* vb = smem + 16384 + p * 8192;
    *(bf16x8*)(kb + row0 * 128 + ((sl0 ^ (row0 & 7)) << 4)) = kr[0];
    *(bf16x8*)(kb + row1 * 128 + ((sl1 ^ (row1 & 7)) << 4)) = kr[1];
    *(bf16x8*)(vb + row0 * 128 + ((sl0 ^ (row0 & 7)) << 4)) = vr[0];
    *(bf16x8*)(vb + row1 * 128 + ((sl1 ^ (row1 & 7)) << 4)) = vr[1];
  };

  f32x4 zero4 = {0.f, 0.f, 0.f, 0.f};
  f32x4 oacc[4];
#pragma unroll
  for (int nt = 0; nt < 4; ++nt) oacc[nt] = zero4;
  float mrun = 0.f, lrun = 0.f;

  load_kv(0);
  float step = 64.f * cdec2;
  float tb = 0.f;
  int p = 0;
  for (int t = 0; t < qt; ++t, tb += step, p ^= 1) {
    stage(p);           // waits vmcnt for kr/vr internally
    load_kv(t + 1);     // prefetch next tile; drains at next stage()
    __syncthreads();    // staged writes visible; prev buffer's readers done
    attn_tile<false>(smem + p * 8192, smem + 16384 + p * 8192, tb - mrun, cbv,
                     qf, oacc, mrun, lrun, lg, lr, il, pbuf);
  }
  stage(p);
  __syncthreads();
  attn_tile<true>(smem + p * 8192, smem + 16384 + p * 8192, tb - mrun, cbv,
                  qf, oacc, mrun, lrun, lg, lr, il, pbuf);

  // ---- epilogue: redistribute l (lane p in 0..15 holds q-row p's sum) ----
  float lfin[4];
  int li = __float_as_int(lrun);
#pragma unroll
  for (int r = 0; r < 4; ++r)
    lfin[r] = __int_as_float(__builtin_amdgcn_ds_bpermute((4 * lg + r) << 2, li));
#pragma unroll
  for (int nt = 0; nt < 4; ++nt)
#pragma unroll
    for (int r = 0; r < 4; ++r) {
      int srow = q0 + w * 16 + lg * 4 + r;
      int col = h * DH + nt * 16 + lr;
      attnout[((size_t)b * S_LEN + srow) * DM + col] = f2bf(oacc[nt][r] / lfin[r]);
    }
}

// ---------------- launch ----------------
extern "C" void kernel_launch(void* const* d_in, const int* in_sizes, int n_in,
                              void* d_out, int out_size, void* d_ws, size_t ws_size,
                              hipStream_t stream) {
  const float* x    = (const float*)d_in[0];
  const float* Wqkv = (const float*)d_in[1];
  const float* Wo   = (const float*)d_in[2];
  const float* log_xi        = (const float*)d_in[3];
  const float* pi_gate_logit = (const float*)d_in[4];
  const float* e_gate_logit  = (const float*)d_in[5];

  u16* xb     = (u16*)d_ws;                 // 4096x1024
  u16* wqkvb  = xb + 4194304;               // 3072x1024
  u16* wob    = wqkvb + 3145728;            // 1024x1024
  u16* qkv    = wob + 1048576;              // 4096x3072
  u16* qrot   = qkv + 12582912;             // 32x2048x64
  u16* krot   = qrot + 4194304;
  u16* vt     = krot + 4194304;             // 32x64x2048
  u16* attno  = vt + 4194304;               // 4096x1024

  conv3_kernel<<<4096, 256, 0, stream>>>(x, Wqkv, Wo, xb, wqkvb, wob);

  gemm_bt<0><<<dim3(24, 32), 256, 0, stream>>>(xb, wqkvb, qkv, 3072, 1024);

  rope_kernel<<<dim3(32, 32), 256, 0, stream>>>(qkv, pi_gate_logit, qrot, krot, vt);

  attn_kernel<<<dim3(32, 32), 256, 0, stream>>>(qrot, krot, vt, log_xi, e_gate_logit, attno);

  gemm_bt<1><<<dim3(8, 32), 256, 0, stream>>>(attno, wob, d_out, 1024, 1024);
}